// Round 5
// baseline (249.583 us; speedup 1.0000x reference)
//
#include <hip/hip_runtime.h>

#define NPOS 21824          // 16384+4096+1024+256+64 positions per image
#define MINS 0.05f

struct Ptrs { const float* cls[5]; const float* reg[5]; const float* ctr[5]; };

__device__ __forceinline__ float sigf(float x){ return 1.0f/(1.0f+expf(-x)); }

// ---------------- Kernel A: score / class / box, 4 lanes per position -------
// Block = 256 threads = 64 positions; level boundaries are block-aligned.
// Lane l of each 4-lane group: cls float4s #l,#4+l,..., reg component l,
// box component l -> coalesced reads and writes, exp() spread over 4 lanes.
__global__ __launch_bounds__(256) void k_score(Ptrs P, float* scoreAll, int* clsAll,
                                               float* boxAll)
{
    int img  = blockIdx.y;
    int blk  = blockIdx.x;           // [0,341)
    int tid  = threadIdx.x;
    int posb = tid >> 2;             // position within block [0,64)
    int l    = tid & 3;              // lane within 4-lane group
    int p    = blk*64 + posb;
    int lvl, base, lw, stride;
    if (blk < 256)      { lvl=0; base=0;     lw=7; stride=8;   }
    else if (blk < 320) { lvl=1; base=16384; lw=6; stride=16;  }
    else if (blk < 336) { lvl=2; base=20480; lw=5; stride=32;  }
    else if (blk < 340) { lvl=3; base=21504; lw=4; stride=64;  }
    else                { lvl=4; base=21760; lw=3; stride=128; }
    int pl = p - base;
    int h = pl >> lw, w = pl & ((1<<lw)-1);
    long long lidx = (long long)img*(1<<(2*lw)) + pl;

    const float4* c4 = (const float4*)(P.cls[lvl] + lidx*80);
    float mx = -3.4e38f; int mi = 0;
#pragma unroll
    for (int j = 0; j < 5; ++j) {
        int k = j*4 + l;
        float4 v = c4[k];
        int cb = k*4;
        if (v.x > mx){mx=v.x; mi=cb;}
        if (v.y > mx){mx=v.y; mi=cb+1;}
        if (v.z > mx){mx=v.z; mi=cb+2;}
        if (v.w > mx){mx=v.w; mi=cb+3;}
    }
#pragma unroll
    for (int d = 1; d < 4; d <<= 1) {
        float omx = __shfl_xor(mx, d);
        int   omi = __shfl_xor(mi, d);
        if (omx > mx || (omx == mx && omi < mi)) { mx = omx; mi = omi; }
    }
    int o = img*NPOS + p;

    // distributed box decode: lane l handles box component l
    float rgv = P.reg[lvl][lidx*4 + l];          // 4 lanes read 16B contiguous
    float e   = expf(rgv);
    float x = (w + 0.5f)*(float)stride;
    float y = (h + 0.5f)*(float)stride;
    float coord = (l & 1) ? y : x;
    float v = (l < 2) ? coord - e : coord + e;
    int iv = (int)v;                              // trunc toward zero == astype(int32)
    iv = (l < 2) ? max(iv, 0) : min(iv, 1023);    // one-sided clamps (match ref)
    boxAll[(long long)o*4 + l] = (float)iv;       // 4 lanes write 16B contiguous

    if (l == 0) {
        float ct = P.ctr[lvl][lidx];
        float sc = sqrtf(sigf(mx)*sigf(ct));      // sigmoid(max)==max(sigmoid)
        scoreAll[o] = sc;
        clsAll[o]   = mi;
    }
}

// ---- exact K-th-largest u32, 3-pass radix (18/8/0), wave suffix scan -------
// Scores are positive floats <= 1.0 -> bits>>18 < 4096 (monotone bins).
__device__ void radix_sel_g(const unsigned int* vals, int N, int K,
                            int* hist, int* wsum, unsigned int* shPref, int* shK,
                            int tid)
{
    if (tid == 0) { *shPref = 0; *shK = K; }
    __syncthreads();
    for (int pass = 0; pass < 3; ++pass) {
        int sh = pass == 0 ? 18 : (pass == 1 ? 8 : 0);
        int nb = pass == 0 ? 4096 : (pass == 1 ? 1024 : 256);
        unsigned int pref = *shPref;
        int K2 = *shK;
        for (int i = tid; i < nb; i += 256) hist[i] = 0;
        __syncthreads();
#pragma unroll 4
        for (int i = tid; i < N; i += 256) {
            unsigned int b = vals[i];
            bool match = (pass == 0) ||
                         (pass == 1 ? ((b >> 18) == (pref >> 18))
                                    : ((b >> 8)  == (pref >> 8)));
            if (match) atomicAdd(&hist[(b >> sh) & (nb - 1)], 1);
        }
        __syncthreads();
        int g = nb >> 8, lo = tid * g, ls = 0;
        for (int q = 0; q < g; ++q) ls += hist[lo + q];
        int lane = tid & 63, wv = tid >> 6;
        int v = ls;
#pragma unroll
        for (int off = 1; off < 64; off <<= 1) {
            int o = __shfl_down(v, off);
            if (lane + off < 64) v += o;
        }
        if (lane == 0) wsum[wv] = v;
        __syncthreads();
        int add = 0;
        for (int q = wv + 1; q < 4; ++q) add += wsum[q];
        int mine  = v + add;             // suffix sum threads [tid..255]
        int above = mine - ls;           // suffix sum threads (tid..255]
        if (above < K2 && mine >= K2) {  // exactly one thread crosses
            int cum = above;
            for (int b = lo + g - 1; b >= lo; --b) {
                cum += hist[b];
                if (cum >= K2) {
                    *shPref = pref | ((unsigned int)b << sh);
                    *shK = K2 - (cum - hist[b]);
                    break;
                }
            }
        }
        __syncthreads();
    }
}

// ---- Kernel B: per-image top-256 + IoU-matrix greedy NMS (8 blocks) --------
// key = (score_bits<<16)|(65535-p): desc key == desc score, ties lower p ==
// reference concat-order argmax tie-break. Image top-256 by key == union
// top-256 by key (any image-rank<256 element has level-rank<1000).
__global__ __launch_bounds__(256) void k_nms3(const float* scoreAll, const int* clsAll,
                                              const float* boxAll, float* out)
{
    __shared__ int hist[4096];
    __shared__ int wsum[4];
    __shared__ unsigned int shPref;
    __shared__ int shK, tick, eqn, shNa, shFB, supFlag, cntR;
    __shared__ unsigned long long lastK;
    __shared__ int eq[256];
    __shared__ unsigned long long sel[256], sorted[256];
    __shared__ float4 sBox[256];
    __shared__ float  sCls[256], sA[256];
    __shared__ unsigned long long supMask[1024];   // 256 rows x 4 words; fallback: red[]
    __shared__ int    accList[100];
    __shared__ float4 accB[100];
    __shared__ float  accA[100];

    int img = blockIdx.x, tid = threadIdx.x;
    const unsigned int* gs = (const unsigned int*)scoreAll + (long long)img*NPOS;
    const float4* gBox = (const float4*)boxAll + (long long)img*NPOS;
    const int*    gCls = clsAll + (long long)img*NPOS;

    radix_sel_g(gs, NPOS, 256, hist, wsum, &shPref, &shK, tid);
    if (tid == 0) { tick = 0; eqn = 0; }
    __syncthreads();
    unsigned int kth = shPref;
    int need = shK;
#pragma unroll 4
    for (int i = tid; i < NPOS; i += 256) {
        unsigned int b = gs[i];
        if (b > kth) {
            int t = atomicAdd(&tick, 1);
            sel[t] = ((unsigned long long)b << 16) | (unsigned)(65535 - i);
        } else if (b == kth) {
            int t = atomicAdd(&eqn, 1);
            if (t < 256) eq[t] = i;
        }
    }
    __syncthreads();
    int m = eqn, nG = tick;              // nG == 256-need
    if (m <= 256) {                      // keep `need` lowest-p ties
        for (int q = tid; q < m; q += 256) {
            int iq = eq[q], r = 0;
            for (int j = 0; j < m; ++j) r += (eq[j] < iq);
            if (r < need)
                sel[nG + r] = ((unsigned long long)kth << 16) | (unsigned)(65535 - iq);
        }
    } else if (tid == 0) {               // unreachable-in-practice fallback
        int cnt = 0;
        for (int i = 0; i < NPOS && cnt < need; ++i)
            if (gs[i] == kth) {
                sel[nG + cnt] = ((unsigned long long)kth << 16) | (unsigned)(65535 - i);
                ++cnt;
            }
    }
    __syncthreads();

    // rank 256 unique keys by counting -> sorted (descending)
    {
        unsigned long long k = sel[tid];
        int r = 0;
        for (int j = 0; j < 256; ++j) r += (sel[j] > k);
        sorted[r] = k;
    }
    __syncthreads();
    {
        int p = 65535 - (int)(sorted[tid] & 0xFFFF);
        float4 b = gBox[p];
        sBox[tid] = b;
        sCls[tid] = (float)gCls[p];
        sA[tid]   = (b.z - b.x)*(b.w - b.y);
    }
    __syncthreads();

    // 256x256 suppression bitmatrix: row t bit j <=> iou(t,j)>0.6, j!=t
    {
        float4 bt = sBox[tid]; float at = sA[tid];
        unsigned long long w0=0, w1=0, w2=0, w3=0;
        for (int j = 0; j < 256; ++j) {
            float4 bj = sBox[j];                       // broadcast LDS read
            float iw = fmaxf(fminf(bt.z,bj.z)-fmaxf(bt.x,bj.x),0.f);
            float ih = fmaxf(fminf(bt.w,bj.w)-fmaxf(bt.y,bj.y),0.f);
            float in_ = iw*ih;
            bool sup = (j != tid) && (in_/(at + sA[j] - in_ + 1e-12f) > 0.6f);
            unsigned long long bit = sup ? (1ull << (j & 63)) : 0ull;
            if (j < 64) w0 |= bit; else if (j < 128) w1 |= bit;
            else if (j < 192) w2 |= bit; else w3 |= bit;
        }
        supMask[tid*4+0]=w0; supMask[tid*4+1]=w1;
        supMask[tid*4+2]=w2; supMask[tid*4+3]=w3;
    }
    __syncthreads();

    // serial greedy scan: 4-word AND per candidate (== sequential NMS)
    if (tid == 0) {
        unsigned long long a0=0, a1=0, a2=0, a3=0;
        int na = 0, fb = 1;
        for (int i = 0; i < 256; ++i) {
            float sc = __uint_as_float((unsigned int)(sorted[i] >> 16));
            if (!(sc > MINS)) { fb = 0; break; }
            bool sup = ((supMask[4*i]&a0)|(supMask[4*i+1]&a1)|
                        (supMask[4*i+2]&a2)|(supMask[4*i+3]&a3)) != 0ull;
            if (!sup) {
                if (i < 64) a0 |= 1ull<<i; else if (i < 128) a1 |= 1ull<<(i-64);
                else if (i < 192) a2 |= 1ull<<(i-128); else a3 |= 1ull<<(i-192);
                accList[na++] = i;
                if (na == 100) { fb = 0; break; }
            }
        }
        shNa = na; shFB = (fb && na < 100) ? 1 : 0; lastK = sorted[255];
    }
    __syncthreads();
    int na = shNa;
    float* outS = out + img*100;
    float* outC = out + 800 + img*100;
    float* outB = out + 1600 + img*400;
    if (tid < 100) {
        if (tid < na) {
            int ix = accList[tid];
            outS[tid] = __uint_as_float((unsigned int)(sorted[ix] >> 16));
            outC[tid] = sCls[ix];
            float4 b = sBox[ix];
            outB[4*tid]=b.x; outB[4*tid+1]=b.y; outB[4*tid+2]=b.z; outB[4*tid+3]=b.w;
            accB[tid] = b; accA[tid] = sA[ix];
        } else {
            outS[tid] = -1.f; outC[tid] = -1.f;
            outB[4*tid]=-1.f; outB[4*tid+1]=-1.f; outB[4*tid+2]=-1.f; outB[4*tid+3]=-1.f;
        }
    }
    __syncthreads();
    if (!shFB) return;

    // ---- exact slow fallback: top-256 exhausted (never on real data) ----
    // Walk remaining union candidates in key order, exact union-membership
    // check (level-rank < 1000). All branches block-uniform.
    unsigned long long* red = supMask;
    while (true) {
        unsigned long long lk = lastK, best = 0;
        for (int i = tid; i < NPOS; i += 256) {
            unsigned long long k = ((unsigned long long)gs[i] << 16) | (unsigned)(65535 - i);
            if (k < lk && k > best) best = k;
        }
        red[tid] = best;
        __syncthreads();
        if (tid == 0) {
            unsigned long long b = 0;
            for (int j = 0; j < 256; ++j) if (red[j] > b) b = red[j];
            red[0] = b;
        }
        __syncthreads();
        best = red[0];
        if (best == 0ull) break;
        float sc = __uint_as_float((unsigned int)(best >> 16));
        if (!(sc > MINS)) break;
        int p = 65535 - (int)(best & 0xFFFF);
        int lvl = p < 16384 ? 0 : p < 20480 ? 1 : p < 21504 ? 2 : p < 21760 ? 3 : 4;
        bool elig = true;
        if (lvl < 3) {
            int base = lvl == 0 ? 0 : (lvl == 1 ? 16384 : 20480);
            int Nl   = lvl == 0 ? 16384 : (lvl == 1 ? 4096 : 1024);
            if (tid == 0) cntR = 0;
            __syncthreads();
            int c = 0;
            for (int q = tid; q < Nl; q += 256) {
                unsigned long long kq = ((unsigned long long)gs[base+q] << 16)
                                        | (unsigned)(65535 - (base + q));
                if (kq > best) ++c;
            }
            atomicAdd(&cntR, c);
            __syncthreads();
            elig = (cntR < 1000);
        }
        if (elig) {
            float4 nb = gBox[p];
            float nA = (nb.z - nb.x)*(nb.w - nb.y);
            if (tid == 0) supFlag = 0;
            __syncthreads();
            if (tid < shNa) {
                float4 ab = accB[tid];
                float iw = fmaxf(fminf(nb.z,ab.z)-fmaxf(nb.x,ab.x),0.f);
                float ih = fmaxf(fminf(nb.w,ab.w)-fmaxf(nb.y,ab.y),0.f);
                float in_ = iw*ih;
                if (in_/(nA + accA[tid] - in_ + 1e-12f) > 0.6f) atomicOr(&supFlag, 1);
            }
            __syncthreads();
            if (!supFlag) {
                if (tid == 0) {
                    int k2 = shNa;
                    outS[k2] = sc; outC[k2] = (float)gCls[p];
                    outB[4*k2]=nb.x; outB[4*k2+1]=nb.y; outB[4*k2+2]=nb.z; outB[4*k2+3]=nb.w;
                    accB[k2] = nb; accA[k2] = nA; shNa = k2 + 1;
                }
                __syncthreads();
                if (shNa >= 100) break;
            }
        }
        if (tid == 0) lastK = best;
        __syncthreads();
    }
}

extern "C" void kernel_launch(void* const* d_in, const int* in_sizes, int n_in,
                              void* d_out, int out_size, void* d_ws, size_t ws_size,
                              hipStream_t stream) {
    Ptrs P;
    bool interleaved = (in_sizes[1] == 8 * 128 * 128 * 4);
    for (int i = 0; i < 5; ++i) {
        if (interleaved) {
            P.cls[i] = (const float*)d_in[3*i];
            P.reg[i] = (const float*)d_in[3*i + 1];
            P.ctr[i] = (const float*)d_in[3*i + 2];
        } else {
            P.cls[i] = (const float*)d_in[i];
            P.reg[i] = (const float*)d_in[5 + i];
            P.ctr[i] = (const float*)d_in[10 + i];
        }
    }

    char* wbase = (char*)d_ws;
    size_t off = 0;
    auto alloc = [&](size_t bytes) -> void* {
        void* r = wbase + off;
        off += (bytes + 255) & ~(size_t)255;
        return r;
    };
    float* scoreAll = (float*)alloc((size_t)8 * NPOS * 4);
    int*   clsAll   = (int*)alloc((size_t)8 * NPOS * 4);
    float* boxAll   = (float*)alloc((size_t)8 * NPOS * 16);

    dim3 gA(341, 8);   // 341*64 = 21824 positions, level boundaries block-aligned
    k_score<<<gA, 256, 0, stream>>>(P, scoreAll, clsAll, boxAll);
    k_nms3 <<<8, 256, 0, stream>>>(scoreAll, clsAll, boxAll, (float*)d_out);
}